// Round 8
// baseline (253.336 us; speedup 1.0000x reference)
//
#include <hip/hip_runtime.h>
#include <hip/hip_bf16.h>

#define N_NODES 20000
#define N_EDGES 640000
#define NRELS 20
#define GEMM_V 1600        // 8 XCDs * 40 tiles * 5 rel-groups (virtual, 35 dead)
#define FILL_BLOCKS 2500   // 640000 / 256

typedef __attribute__((ext_vector_type(8))) short short8;
typedef __attribute__((ext_vector_type(8))) unsigned short ushort8;
typedef __attribute__((ext_vector_type(4))) float floatx4;
typedef unsigned short u16;
typedef unsigned int u32;

__device__ __forceinline__ float bf2f(u16 u){
  union { u32 i; float f; } v; v.i = ((u32)u) << 16; return v.f;
}
__device__ __forceinline__ u16 f2bf(float f){
  __hip_bfloat16 b = __float2bfloat16(f);
  return __builtin_bit_cast(u16, b);
}

// ---------------- K0: fused {cast h->bf16 + 4-shard count/rank} | {wfrag} ----
// wfrag layout: [rel][frag = ks*8+nf][lane][8 bf16]  (MFMA fragment order)
__global__ __launch_bounds__(256) void k_prep(
    const float* __restrict__ h, u16* __restrict__ hb,
    const int* __restrict__ dst, int* __restrict__ counts4, int* __restrict__ rank,
    const float* __restrict__ weight, const float* __restrict__ w_comp,
    u16* __restrict__ wfrag){
  const int b = blockIdx.x;
  if (b < 2500){
    int tidg = b * 256 + threadIdx.x;
    int i = tidg * 4;
    float4 v = *(const float4*)(h + i);
    u16 o[4] = { f2bf(v.x), f2bf(v.y), f2bf(v.z), f2bf(v.w) };
    *(ushort4*)(hb + i) = *(ushort4*)o;
    rank[tidg] = atomicAdd(&counts4[(b & 3) * N_NODES + dst[tidg]], 1);
  } else {
    int f = (b - 2500) * 256 + threadIdx.x;      // < 20*128*128 exactly
    int i  = f & 127;
    int o  = (f >> 7) & 127;
    int r  = f >> 14;
    int q  = r * 128 + i;                        // reference reshape semantics
    int rr = q % 20, ii = q / 20;
    float acc = 0.f;
    #pragma unroll
    for (int bb = 0; bb < 8; ++bb)
      acc += w_comp[rr * 8 + bb] * weight[ii * 1024 + bb * 128 + o];
    int ks = i >> 5, sub = (i >> 3) & 3, j = i & 7, nf = o >> 4;
    int l  = (sub << 4) | (o & 15);
    wfrag[((r * 32 + ks * 8 + nf) * 64 + l) * 8 + j] = f2bf(acc);
  }
}

// ---------------- K1: scan (4-shard) -> offs + per-shard bases ---------------
__global__ __launch_bounds__(1024) void k_scan(const int* __restrict__ counts4,
    int* __restrict__ offs, int* __restrict__ soff){
  __shared__ int sums[1024];
  const int t = threadIdx.x;
  const int base = t * 20;
  int loc[20]; int s = 0;
  #pragma unroll
  for (int j = 0; j < 20; ++j){
    int idx = base + j;
    int tot = 0;
    if (idx < N_NODES){
      #pragma unroll
      for (int sh = 0; sh < 4; ++sh) tot += counts4[sh * N_NODES + idx];
    }
    loc[j] = tot; s += tot;
  }
  sums[t] = s;
  __syncthreads();
  for (int off = 1; off < 1024; off <<= 1){
    int v = (t >= off) ? sums[t - off] : 0;
    __syncthreads();
    sums[t] += v;
    __syncthreads();
  }
  int run = (t == 0) ? 0 : sums[t - 1];
  #pragma unroll
  for (int j = 0; j < 20; ++j){
    int idx = base + j;
    if (idx < N_NODES){
      offs[idx] = run;
      int c0 = counts4[idx];
      int c1 = counts4[N_NODES + idx];
      int c2 = counts4[2 * N_NODES + idx];
      soff[idx]               = run;
      soff[N_NODES + idx]     = run + c0;
      soff[2 * N_NODES + idx] = run + c0 + c1;
      soff[3 * N_NODES + idx] = run + c0 + c1 + c2;
      run += loc[j];
    }
  }
  if (t == 0) offs[N_NODES] = N_EDGES;
}

// ---------------- K2: RB=4 GEMM (A-regs, B fragment-major LDS) + CSR fill ----
// xW rows PERMUTED: position p = (c&15)*8 + (c>>4); stores are ushort8.
__global__ __launch_bounds__(256, 4) void k_gemm_fill(
    const u16* __restrict__ hb, const u16* __restrict__ wfrag, u16* __restrict__ xW,
    const int* __restrict__ dst, const int* __restrict__ srcv,
    const int* __restrict__ ety, const int* __restrict__ soff,
    const int* __restrict__ rank, int* __restrict__ gidx){
  if (blockIdx.x >= GEMM_V){                     // ---- fill role ----
    int e = (blockIdx.x - GEMM_V) * 256 + threadIdx.x;
    if (e < N_EDGES){
      int sh = (e >> 8) & 3;
      int p  = soff[sh * N_NODES + dst[e]] + rank[e];
      gidx[p] = ety[e] * N_NODES + srcv[e];
    }
    return;
  }
  // ---- gemm role: XCD-co-located 64-row tile x 4 relations ----
  const int vb = blockIdx.x;
  const int x  = vb & 7;                         // XCD (bid % 8 round-robin)
  const int k  = vb >> 3;                        // 0..199
  const int tile = x * 40 + k / 5;               // 40 tiles per XCD
  const int rg   = k % 5;
  if (tile >= 313) return;
  __shared__ u16 Bs[16384];                      // 32 KB fragment-major
  const int m0   = tile * 64;
  const int tid  = threadIdx.x;
  const int wave = tid >> 6, lane = tid & 63;
  // A fragments in registers (one 16-row m-frag per wave)
  short8 a[4];
  const int arow = m0 + wave * 16 + (lane & 15);
  const int ak   = (lane >> 4) * 8;
  const short8 az = __builtin_bit_cast(short8, make_int4(0, 0, 0, 0));
  const bool aok = arow < N_NODES;
  #pragma unroll
  for (int ks = 0; ks < 4; ++ks)
    a[ks] = aok ? *(const short8*)(hb + (size_t)arow * 128 + ks * 32 + ak) : az;
  const char* lbase = (const char*)Bs + lane * 16;
  for (int rb = 0; rb < 4; ++rb){
    const int rel = rg * 4 + rb;
    __syncthreads();                             // prior-phase B reads done
    {                                            // linear 32KB stage, coalesced
      const u16* wb = wfrag + rel * 16384;
      #pragma unroll
      for (int jj = 0; jj < 8; ++jj){
        int idx = tid + jj * 256;
        *(int4*)((char*)Bs + idx * 16) = *(const int4*)(wb + idx * 8);
      }
    }
    __syncthreads();
    floatx4 acc[8] = {};
    #pragma unroll
    for (int ks = 0; ks < 4; ++ks)
      #pragma unroll
      for (int nf = 0; nf < 8; ++nf){
        short8 bfr = *(const short8*)(lbase + ((ks * 8 + nf) << 10));
        acc[nf] = __builtin_amdgcn_mfma_f32_16x16x32_bf16(a[ks], bfr, acc[nf], 0, 0, 0);
      }
    const size_t rbase = (size_t)rel * N_NODES;
    #pragma unroll
    for (int j = 0; j < 4; ++j){
      int row = m0 + wave * 16 + ((lane >> 4) << 2) + j;   // C/D row=(l>>4)*4+j
      if (row < N_NODES){
        ushort8 u;
        #pragma unroll
        for (int nf = 0; nf < 8; ++nf) u[nf] = f2bf(acc[nf][j]);
        *(ushort8*)(xW + (rbase + row) * 128 + (lane & 15) * 8) = u;
      }
    }
  }
}

// ---------------- K3: gather + segment-sum + relu (int4 loads, 16 lanes/node)
__global__ __launch_bounds__(256) void k_agg(const int* __restrict__ offs,
    const int* __restrict__ gidx, const u16* __restrict__ xW, float* __restrict__ out){
  const int n = blockIdx.x * 16 + (threadIdx.x >> 4);   // 16 nodes/block
  const int q = threadIdx.x & 15;                        // 16B chunk owner
  const int b0 = offs[n], b1 = offs[n + 1];
  float acc[2][8];
  #pragma unroll
  for (int bk = 0; bk < 2; ++bk)
    #pragma unroll
    for (int m = 0; m < 8; ++m) acc[bk][m] = 0.f;
  int e = b0;
  for (; e + 8 <= b1; e += 8){
    int g[8];
    #pragma unroll
    for (int j = 0; j < 8; ++j) g[j] = gidx[e + j];
    #pragma unroll
    for (int j = 0; j < 8; ++j){
      int4 v = *(const int4*)(xW + (size_t)g[j] * 128 + q * 8);
      float* A = acc[j & 1];
      u32 w;
      w = (u32)v.x; A[0] += bf2f((u16)(w & 0xffffu)); A[1] += bf2f((u16)(w >> 16));
      w = (u32)v.y; A[2] += bf2f((u16)(w & 0xffffu)); A[3] += bf2f((u16)(w >> 16));
      w = (u32)v.z; A[4] += bf2f((u16)(w & 0xffffu)); A[5] += bf2f((u16)(w >> 16));
      w = (u32)v.w; A[6] += bf2f((u16)(w & 0xffffu)); A[7] += bf2f((u16)(w >> 16));
    }
  }
  for (; e < b1; ++e){
    int4 v = *(const int4*)(xW + (size_t)gidx[e] * 128 + q * 8);
    float* A = acc[0];
    u32 w;
    w = (u32)v.x; A[0] += bf2f((u16)(w & 0xffffu)); A[1] += bf2f((u16)(w >> 16));
    w = (u32)v.y; A[2] += bf2f((u16)(w & 0xffffu)); A[3] += bf2f((u16)(w >> 16));
    w = (u32)v.z; A[4] += bf2f((u16)(w & 0xffffu)); A[5] += bf2f((u16)(w >> 16));
    w = (u32)v.w; A[6] += bf2f((u16)(w & 0xffffu)); A[7] += bf2f((u16)(w >> 16));
  }
  // position p = q*8+m -> channel c = m*16 + q
  #pragma unroll
  for (int m = 0; m < 8; ++m)
    out[(size_t)n * 128 + m * 16 + q] = fmaxf(acc[0][m] + acc[1][m], 0.f);
}

// ---------------- launcher ---------------------------------------------------
extern "C" void kernel_launch(void* const* d_in, const int* in_sizes, int n_in,
                              void* d_out, int out_size, void* d_ws, size_t ws_size,
                              hipStream_t stream){
  const float* h      = (const float*)d_in[0];
  const float* weight = (const float*)d_in[1];
  const float* w_comp = (const float*)d_in[2];
  const int* src      = (const int*)d_in[3];
  const int* dst      = (const int*)d_in[4];
  const int* etype    = (const int*)d_in[5];
  float* out = (float*)d_out;

  char* p = (char*)d_ws;
  u16* xW      = (u16*)p;  p += 102400000;       // [20][20000][128] bf16 (perm rows)
  u16* hb      = (u16*)p;  p += 5120000;
  u16* wfrag   = (u16*)p;  p += 655360;
  int* counts4 = (int*)p;  p += 320000;          // 4 shards x 20000
  int* offs    = (int*)p;  p += 80128;           // 20001 ints + pad
  int* soff    = (int*)p;  p += 320000;          // 4 shards x 20000 bases
  int* rank    = (int*)p;  p += 2560000;
  int* gidx    = (int*)p;  /* 2,560,000 B */     // total ~114 MB

  hipMemsetAsync(counts4, 0, 4 * N_NODES * sizeof(int), stream);
  k_prep<<<dim3(3780), dim3(256), 0, stream>>>(h, hb, dst, counts4, rank,
                                               weight, w_comp, wfrag);
  k_scan<<<dim3(1), dim3(1024), 0, stream>>>(counts4, offs, soff);
  k_gemm_fill<<<dim3(GEMM_V + FILL_BLOCKS), dim3(256), 0, stream>>>(
      hb, wfrag, xW, dst, src, etype, soff, rank, gidx);
  k_agg<<<dim3(N_NODES / 16), dim3(256), 0, stream>>>(offs, gidx, xW, out);
}

// Round 9
// 166.078 us; speedup vs baseline: 1.5254x; 1.5254x over previous
//
#include <hip/hip_runtime.h>
#include <hip/hip_bf16.h>

#define N_NODES 20000
#define N_EDGES 640000
#define NRELS 20
#define MAXDEG 96
#define GEMM_V 1600        // 8 XCDs * 40 tiles * 5 rel-groups (virtual, 35 dead)
#define FILL_BLOCKS 2500   // 640000 / 256

typedef __attribute__((ext_vector_type(8))) short short8;
typedef __attribute__((ext_vector_type(8))) unsigned short ushort8;
typedef __attribute__((ext_vector_type(4))) float floatx4;
typedef unsigned short u16;
typedef unsigned int u32;

__device__ __forceinline__ float bf2f(u16 u){
  union { u32 i; float f; } v; v.i = ((u32)u) << 16; return v.f;
}
__device__ __forceinline__ u16 f2bf(float f){
  __hip_bfloat16 b = __float2bfloat16(f);
  return __builtin_bit_cast(u16, b);
}

// ---------------- K0: fused {cast h->bf16 + count + rank} | {wfrag} ----------
// wfrag layout: [rel][frag = ks*8+nf][lane][8 bf16]  (MFMA fragment order)
__global__ __launch_bounds__(256) void k_prep(
    const float* __restrict__ h, u16* __restrict__ hb,
    const int* __restrict__ dst, int* __restrict__ counts, int* __restrict__ rank,
    const float* __restrict__ weight, const float* __restrict__ w_comp,
    u16* __restrict__ wfrag){
  const int b = blockIdx.x;
  if (b < 2500){
    int tidg = b * 256 + threadIdx.x;
    int i = tidg * 4;
    float4 v = *(const float4*)(h + i);
    u16 o[4] = { f2bf(v.x), f2bf(v.y), f2bf(v.z), f2bf(v.w) };
    *(ushort4*)(hb + i) = *(ushort4*)o;
    rank[tidg] = atomicAdd(&counts[dst[tidg]], 1);
  } else {
    int f = (b - 2500) * 256 + threadIdx.x;      // < 20*128*128 exactly
    int i  = f & 127;
    int o  = (f >> 7) & 127;
    int r  = f >> 14;
    int q  = r * 128 + i;                        // reference reshape semantics
    int rr = q % 20, ii = q / 20;
    float acc = 0.f;
    #pragma unroll
    for (int bb = 0; bb < 8; ++bb)
      acc += w_comp[rr * 8 + bb] * weight[ii * 1024 + bb * 128 + o];
    int ks = i >> 5, sub = (i >> 3) & 3, j = i & 7, nf = o >> 4;
    int l  = (sub << 4) | (o & 15);
    wfrag[((r * 32 + ks * 8 + nf) * 64 + l) * 8 + j] = f2bf(acc);
  }
}

// ---------------- K1: RB=4 GEMM (A-regs, B fragment-major LDS) + bucket fill -
// xW rows PERMUTED: position p = (c&15)*8 + (c>>4); stores are ushort8.
__global__ __launch_bounds__(256, 4) void k_gemm_fill(
    const u16* __restrict__ hb, const u16* __restrict__ wfrag, u16* __restrict__ xW,
    const int* __restrict__ dst, const int* __restrict__ srcv,
    const int* __restrict__ ety, const int* __restrict__ rank,
    int* __restrict__ gidx){
  if (blockIdx.x >= GEMM_V){                     // ---- fill role ----
    int e = (blockIdx.x - GEMM_V) * 256 + threadIdx.x;
    if (e < N_EDGES)
      gidx[dst[e] * MAXDEG + rank[e]] = ety[e] * N_NODES + srcv[e];
    return;
  }
  // ---- gemm role: XCD-co-located 64-row tile x 4 relations ----
  const int vb = blockIdx.x;
  const int x  = vb & 7;                         // XCD (bid % 8 round-robin)
  const int k  = vb >> 3;                        // 0..199
  const int tile = x * 40 + k / 5;               // 40 tiles per XCD
  const int rg   = k % 5;
  if (tile >= 313) return;
  __shared__ u16 Bs[16384];                      // 32 KB fragment-major
  const int m0   = tile * 64;
  const int tid  = threadIdx.x;
  const int wave = tid >> 6, lane = tid & 63;
  // A fragments in registers (one 16-row m-frag per wave)
  short8 a[4];
  const int arow = m0 + wave * 16 + (lane & 15);
  const int ak   = (lane >> 4) * 8;
  const short8 az = __builtin_bit_cast(short8, make_int4(0, 0, 0, 0));
  const bool aok = arow < N_NODES;
  #pragma unroll
  for (int ks = 0; ks < 4; ++ks)
    a[ks] = aok ? *(const short8*)(hb + (size_t)arow * 128 + ks * 32 + ak) : az;
  const char* lbase = (const char*)Bs + lane * 16;
  for (int rb = 0; rb < 4; ++rb){
    const int rel = rg * 4 + rb;
    __syncthreads();                             // prior-phase B reads done
    {                                            // linear 32KB stage, coalesced
      const u16* wb = wfrag + rel * 16384;
      #pragma unroll
      for (int jj = 0; jj < 8; ++jj){
        int idx = tid + jj * 256;
        *(int4*)((char*)Bs + idx * 16) = *(const int4*)(wb + idx * 8);
      }
    }
    __syncthreads();
    floatx4 acc[8] = {};
    #pragma unroll
    for (int ks = 0; ks < 4; ++ks)
      #pragma unroll
      for (int nf = 0; nf < 8; ++nf){
        short8 bfr = *(const short8*)(lbase + ((ks * 8 + nf) << 10));
        acc[nf] = __builtin_amdgcn_mfma_f32_16x16x32_bf16(a[ks], bfr, acc[nf], 0, 0, 0);
      }
    const size_t rbase = (size_t)rel * N_NODES;
    #pragma unroll
    for (int j = 0; j < 4; ++j){
      int row = m0 + wave * 16 + ((lane >> 4) << 2) + j;   // C/D row=(l>>4)*4+j
      if (row < N_NODES){
        ushort8 u;
        #pragma unroll
        for (int nf = 0; nf < 8; ++nf) u[nf] = f2bf(acc[nf][j]);
        *(ushort8*)(xW + (rbase + row) * 128 + (lane & 15) * 8) = u;
      }
    }
  }
}

// ---------------- K2: gather + segment-sum + relu (int4 loads, 16 lanes/node)
__global__ __launch_bounds__(256) void k_agg(const int* __restrict__ counts,
    const int* __restrict__ gidx, const u16* __restrict__ xW, float* __restrict__ out){
  const int n = blockIdx.x * 16 + (threadIdx.x >> 4);   // 16 nodes/block
  const int q = threadIdx.x & 15;                        // 16B chunk owner
  const int len = counts[n];
  const int* gb = gidx + n * MAXDEG;
  float acc[2][8];
  #pragma unroll
  for (int bk = 0; bk < 2; ++bk)
    #pragma unroll
    for (int m = 0; m < 8; ++m) acc[bk][m] = 0.f;
  int e = 0;
  for (; e + 8 <= len; e += 8){
    int g[8];
    #pragma unroll
    for (int j = 0; j < 8; ++j) g[j] = gb[e + j];
    #pragma unroll
    for (int j = 0; j < 8; ++j){
      int4 v = *(const int4*)(xW + (size_t)g[j] * 128 + q * 8);
      float* A = acc[j & 1];
      u32 w;
      w = (u32)v.x; A[0] += bf2f((u16)(w & 0xffffu)); A[1] += bf2f((u16)(w >> 16));
      w = (u32)v.y; A[2] += bf2f((u16)(w & 0xffffu)); A[3] += bf2f((u16)(w >> 16));
      w = (u32)v.z; A[4] += bf2f((u16)(w & 0xffffu)); A[5] += bf2f((u16)(w >> 16));
      w = (u32)v.w; A[6] += bf2f((u16)(w & 0xffffu)); A[7] += bf2f((u16)(w >> 16));
    }
  }
  for (; e < len; ++e){
    int4 v = *(const int4*)(xW + (size_t)gb[e] * 128 + q * 8);
    float* A = acc[0];
    u32 w;
    w = (u32)v.x; A[0] += bf2f((u16)(w & 0xffffu)); A[1] += bf2f((u16)(w >> 16));
    w = (u32)v.y; A[2] += bf2f((u16)(w & 0xffffu)); A[3] += bf2f((u16)(w >> 16));
    w = (u32)v.z; A[4] += bf2f((u16)(w & 0xffffu)); A[5] += bf2f((u16)(w >> 16));
    w = (u32)v.w; A[6] += bf2f((u16)(w & 0xffffu)); A[7] += bf2f((u16)(w >> 16));
  }
  // position p = q*8+m -> channel c = m*16 + q
  #pragma unroll
  for (int m = 0; m < 8; ++m)
    out[(size_t)n * 128 + m * 16 + q] = fmaxf(acc[0][m] + acc[1][m], 0.f);
}

// ---------------- launcher ---------------------------------------------------
extern "C" void kernel_launch(void* const* d_in, const int* in_sizes, int n_in,
                              void* d_out, int out_size, void* d_ws, size_t ws_size,
                              hipStream_t stream){
  const float* h      = (const float*)d_in[0];
  const float* weight = (const float*)d_in[1];
  const float* w_comp = (const float*)d_in[2];
  const int* src      = (const int*)d_in[3];
  const int* dst      = (const int*)d_in[4];
  const int* etype    = (const int*)d_in[5];
  float* out = (float*)d_out;

  char* p = (char*)d_ws;
  u16* xW      = (u16*)p;  p += 102400000;       // [20][20000][128] bf16 (perm rows)
  u16* hb      = (u16*)p;  p += 5120000;
  u16* wfrag   = (u16*)p;  p += 655360;
  int* counts  = (int*)p;  p += 80000;
  int* rank    = (int*)p;  p += 2560000;
  int* gidx    = (int*)p;  /* 20000*96*4 = 7,680,000 B */   // total ~118.5 MB

  hipMemsetAsync(counts, 0, N_NODES * sizeof(int), stream);
  k_prep<<<dim3(3780), dim3(256), 0, stream>>>(h, hb, dst, counts, rank,
                                               weight, w_comp, wfrag);
  k_gemm_fill<<<dim3(GEMM_V + FILL_BLOCKS), dim3(256), 0, stream>>>(
      hb, wfrag, xW, dst, src, etype, rank, gidx);
  k_agg<<<dim3(N_NODES / 16), dim3(256), 0, stream>>>(counts, gidx, xW, out);
}